// Round 1
// baseline (552.759 us; speedup 1.0000x reference)
//
#include <hip/hip_runtime.h>
#include <math.h>

#define B_    32
#define H_    32
#define KVH_  8
#define D_    128
#define S_    2048
#define REP   4            // H_/KVH_
#define PAIRS 256          // B_*KVH_
#define SCALE 0.08838834764831845f

typedef unsigned int u32;

// async global->LDS DMA, 16B per lane, lands at lds_base + lane*16
__device__ __forceinline__ void dma16(const float* g, float* l) {
    __builtin_amdgcn_global_load_lds(
        (const __attribute__((address_space(1))) u32*)g,
        (__attribute__((address_space(3))) u32*)l,
        16, 0, 0);
}

#define WAITVM(N) asm volatile("s_waitcnt vmcnt(" #N ")" ::: "memory")

// ---- one-shot q rope (double precision, matches reference path) + invf table ----
__global__ __launch_bounds__(64) void rope_q(
    const float* __restrict__ query,
    const int*   __restrict__ positions,
    float* __restrict__ q_rot,
    float* __restrict__ invf_tab)
{
    const int head = blockIdx.x;          // b*H_ + h
    const int b    = head >> 5;           // H_ = 32
    const int j    = threadIdx.x;         // freq index 0..63
    const double invf = exp(-(double)j * (9.210340371976184 / 64.0));
    if (head == 0) invf_tab[j] = (float)invf;
    const int posq = positions[b * S_ + (S_ - 1)];
    const double fr = (double)posq * invf;
    const float cs = (float)cos(fr), sn = (float)sin(fr);
    const float* q = query + (size_t)head * D_;
    const float lo = q[j], hi = q[64 + j];
    float* o = q_rot + (size_t)head * D_;
    o[j]      = (lo * cs - hi * sn) * SCALE;
    o[64 + j] = (hi * cs + lo * sn) * SCALE;
}

// k_cache/v_cache: [NUM_BLOCKS, 16, KVH, D] flat; token row stride = KVH*D = 1024 floats.
// One WAVE per chunk of S_/cpp tokens; 2 waves (2 chunks) per 128-thread block.
// Wave-private LDS: [2 bufs][k-lo 1KB | k-hi 1KB | v-lo 1KB | v-hi 1KB] + slot/pos arrays.
extern __shared__ char smem_raw[];

__global__ __launch_bounds__(128, 4) void pa_main(
    const float* __restrict__ query,
    const float* __restrict__ k_cache,
    const float* __restrict__ v_cache,
    const int*   __restrict__ slot_map,
    const int*   __restrict__ positions,
    const float* __restrict__ q_rot,
    const float* __restrict__ invf_tab,
    float* __restrict__ ws_l,    // [PAIRS*cpp*4]
    float* __restrict__ ws_acc,  // [PAIRS*cpp*4*128]
    float* __restrict__ out,     // used when cpp==1
    int cpp, int wpb, int use_qrot)
{
    const int w     = threadIdx.x >> 6;
    const int ln    = threadIdx.x & 63;
    const int g     = ln & 15;            // dim group: dims [4g..4g+3] and [64+4g..64+4g+3]
    const int ts    = ln >> 4;            // token slot within pass (0..3)
    const int chunk = S_ / cpp;
    const int gch   = blockIdx.x * wpb + w;   // global chunk id
    const int pair  = gch / cpp;
    const int c     = gch - pair * cpp;
    const int b     = pair >> 3;
    const int kvh   = pair & 7;
    const int t0    = c * chunk;
    const int bS    = b * S_;
    const int passes = chunk >> 2;

    char*  wbase = smem_raw + (size_t)w * (8192 + 8 * chunk);
    float* buf   = (float*)wbase;             // 2 x 1024 floats (2 x 4KB)
    int*   ls    = (int*)(wbase + 8192);
    int*   lp    = ls + chunk;

    // ---- stage slot/pos for this wave's chunk into LDS (keeps loop VMEM = DMAs only) ----
    for (int t = ln; t < chunk; t += 64) {
        ls[t] = slot_map[bS + t0 + t];
        lp[t] = positions[bS + t0 + t];
    }

    // ---- q (already rope'd + scaled) and invf ----
    float ql[4][4], qh[4][4], invf[4];
    if (use_qrot) {
        float4 iv = ((const float4*)invf_tab)[g];
        invf[0] = iv.x; invf[1] = iv.y; invf[2] = iv.z; invf[3] = iv.w;
        #pragma unroll
        for (int hh = 0; hh < REP; hh++) {
            const float4* qb = (const float4*)(q_rot + (size_t)(b * H_ + kvh * REP + hh) * D_);
            float4 a = qb[g], cc = qb[16 + g];
            ql[hh][0] = a.x;  ql[hh][1] = a.y;  ql[hh][2] = a.z;  ql[hh][3] = a.w;
            qh[hh][0] = cc.x; qh[hh][1] = cc.y; qh[hh][2] = cc.z; qh[hh][3] = cc.w;
        }
    } else {
        // fallback: inline double-precision rope (workspace too small for q_rot)
        #pragma unroll
        for (int j = 0; j < 4; j++)
            invf[j] = (float)exp(-(double)(4 * g + j) * (9.210340371976184 / 64.0));
        const int posq = positions[bS + (S_ - 1)];
        #pragma unroll
        for (int hh = 0; hh < REP; hh++) {
            const float4* qb = (const float4*)(query + (size_t)(b * H_ + kvh * REP + hh) * D_);
            float4 a = qb[g], cc = qb[16 + g];
            float al[4] = {a.x, a.y, a.z, a.w};
            float ah[4] = {cc.x, cc.y, cc.z, cc.w};
            #pragma unroll
            for (int j = 0; j < 4; j++) {
                double fr = (double)posq * exp(-(double)(4 * g + j) * (9.210340371976184 / 64.0));
                float cs = (float)cos(fr), sn = (float)sin(fr);
                ql[hh][j] = (al[j] * cs - ah[j] * sn) * SCALE;
                qh[hh][j] = (ah[j] * cs + al[j] * sn) * SCALE;
            }
        }
    }

    float acc_lo[4][4] = {};
    float acc_hi[4][4] = {};
    float lsum[4] = {0.f, 0.f, 0.f, 0.f};

    // issue the 4 DMA loads (K lo/hi, V lo/hi) for pass pi into buffer bi
    auto issue = [&](int pi, int bi) {
        const int tix = pi * 4 + ts;
        const int sl  = ls[tix];
        const int sc  = sl < 0 ? 0 : sl;
        const int ro  = (sc >> 4) * 16384 + (sc & 15) * 1024 + kvh * 128 + 4 * g;
        const float* kr = k_cache + ro;
        const float* vr = v_cache + ro;
        float* bp = buf + bi * 1024;
        dma16(kr,      bp);          // k dims [0..63]   -> f4 slot ln
        dma16(kr + 64, bp + 256);    // k dims [64..127] -> f4 slot 64+ln
        dma16(vr,      bp + 512);
        dma16(vr + 64, bp + 768);
    };

    issue(0, 0);
    for (int i = 0; i < passes; ++i) {
        // issue next pass (clamped on last iter -> uniform vmcnt bookkeeping)
        const int ni = (i + 1 < passes) ? i + 1 : i;
        issue(ni, (i + 1) & 1);

        WAITVM(4);                          // drain pass-i DMAs; keep pass-(i+1) in flight
        __builtin_amdgcn_sched_barrier(0);

        const float4* bf4 = (const float4*)(buf + (i & 1) * 1024);
        float4 k1 = bf4[ln];
        float4 k2 = bf4[64 + ln];

        const int tix = i * 4 + ts;
        const int sl  = ls[tix];
        const float m  = (sl >= 0) ? 1.f : 0.f;
        const float pf = (float)lp[tix];

        float kl[4], kh[4];
        {
            float kx[4] = {k1.x, k1.y, k1.z, k1.w};
            float ky[4] = {k2.x, k2.y, k2.z, k2.w};
            #pragma unroll
            for (int j = 0; j < 4; j++) {
                float fr = pf * invf[j];
                float sn, cs;
                __sincosf(fr, &sn, &cs);
                kl[j] = (kx[j] * cs - ky[j] * sn) * m;
                kh[j] = (ky[j] * cs + kx[j] * sn) * m;
            }
        }

        float p[4];
        #pragma unroll
        for (int hh = 0; hh < 4; hh++) {
            float t = ql[hh][0] * kl[0];
            t += ql[hh][1] * kl[1];
            t += ql[hh][2] * kl[2];
            t += ql[hh][3] * kl[3];
            t += qh[hh][0] * kh[0];
            t += qh[hh][1] * kh[1];
            t += qh[hh][2] * kh[2];
            t += qh[hh][3] * kh[3];
            p[hh] = t;
        }
        #pragma unroll
        for (int hh = 0; hh < 4; hh++) {
            #pragma unroll
            for (int mm = 1; mm < 16; mm <<= 1)
                p[hh] += __shfl_xor(p[hh], mm);
        }

        // V read deferred until after the score reduce (lower register peak)
        float4 v1 = bf4[128 + ln];
        float4 v2 = bf4[192 + ln];
        float vx[4] = {v1.x * m, v1.y * m, v1.z * m, v1.w * m};
        float vy[4] = {v2.x * m, v2.y * m, v2.z * m, v2.w * m};

        #pragma unroll
        for (int hh = 0; hh < 4; hh++) {
            const float wgt = __expf(p[hh]);   // invalid slots: p==0 -> w==1, matches reference
            lsum[hh] += wgt;
            #pragma unroll
            for (int j = 0; j < 4; j++) {
                acc_lo[hh][j] += wgt * vx[j];
                acc_hi[hh][j] += wgt * vy[j];
            }
        }
    }
    WAITVM(0);   // drain the duplicate last-pass DMA before wave exit (LDS reuse safety)

    // ---- merge the 4 token slots within the wave ----
    #pragma unroll
    for (int hh = 0; hh < 4; hh++) {
        lsum[hh] += __shfl_xor(lsum[hh], 16);
        lsum[hh] += __shfl_xor(lsum[hh], 32);
        #pragma unroll
        for (int j = 0; j < 4; j++) {
            acc_lo[hh][j] += __shfl_xor(acc_lo[hh][j], 16);
            acc_lo[hh][j] += __shfl_xor(acc_lo[hh][j], 32);
            acc_hi[hh][j] += __shfl_xor(acc_hi[hh][j], 16);
            acc_hi[hh][j] += __shfl_xor(acc_hi[hh][j], 32);
        }
    }

    if (cpp > 1) {
        if (ln < 16) {
            const size_t base = (size_t)(pair * cpp + c) * 4;
            #pragma unroll
            for (int hh = 0; hh < 4; hh++) {
                float4* dst = (float4*)(ws_acc + (base + hh) * 128);
                dst[g]      = make_float4(acc_lo[hh][0], acc_lo[hh][1], acc_lo[hh][2], acc_lo[hh][3]);
                dst[16 + g] = make_float4(acc_hi[hh][0], acc_hi[hh][1], acc_hi[hh][2], acc_hi[hh][3]);
            }
            if (ln == 0)
                *(float4*)(ws_l + base) = make_float4(lsum[0], lsum[1], lsum[2], lsum[3]);
        }
    } else {
        if (ln < 16) {
            #pragma unroll
            for (int hh = 0; hh < 4; hh++) {
                const float r = 1.f / lsum[hh];
                float4* dst = (float4*)(out + (size_t)(b * H_ + kvh * REP + hh) * D_);
                dst[g]      = make_float4(acc_lo[hh][0] * r, acc_lo[hh][1] * r, acc_lo[hh][2] * r, acc_lo[hh][3] * r);
                dst[16 + g] = make_float4(acc_hi[hh][0] * r, acc_hi[hh][1] * r, acc_hi[hh][2] * r, acc_hi[hh][3] * r);
            }
        }
    }
}

__global__ __launch_bounds__(512) void pa_reduce(
    const float* __restrict__ ws_l,
    const float* __restrict__ ws_acc,
    float* __restrict__ out,
    int cpp)
{
    const int pair = blockIdx.x;
    const int b = pair >> 3, kvh = pair & 7;
    const int hh = threadIdx.x >> 7;
    const int d  = threadIdx.x & 127;
    float a = 0.f;
    for (int s = 0; s < cpp; s++)
        a += ws_acc[((size_t)(pair * cpp + s) * 4 + hh) * 128 + d];
    float lt = 0.f;
    for (int s = 0; s < cpp; s++)
        lt += ws_l[(pair * cpp + s) * 4 + hh];
    out[((size_t)(b * H_ + kvh * REP + hh)) * D_ + d] = a / lt;
}

extern "C" void kernel_launch(void* const* d_in, const int* in_sizes, int n_in,
                              void* d_out, int out_size, void* d_ws, size_t ws_size,
                              hipStream_t stream) {
    const float* query = (const float*)d_in[0];
    const float* kc    = (const float*)d_in[1];
    const float* vc    = (const float*)d_in[2];
    const int*   sm    = (const int*)d_in[3];
    const int*   pos   = (const int*)d_in[4];
    float* out = (float*)d_out;

    const size_t qrot_f = (size_t)B_ * H_ * D_ + 64;   // q_rot + invf table (floats)
    int cpp = 1;
    int use_qrot = 0;
    const int cands[5] = {32, 16, 8, 4, 2};
    for (int ci = 0; ci < 5; ci++) {
        size_t need = (qrot_f + (size_t)PAIRS * cands[ci] * 516) * sizeof(float);
        if (ws_size >= need) { cpp = cands[ci]; use_qrot = 1; break; }
    }
    if (cpp == 1 && ws_size >= qrot_f * sizeof(float)) use_qrot = 1;

    float* q_rot    = (float*)d_ws;
    float* invf_tab = q_rot + (size_t)B_ * H_ * D_;
    float* ws_l     = use_qrot ? (invf_tab + 64) : (float*)d_ws;
    float* ws_acc   = ws_l + (size_t)PAIRS * cpp * 4;

    if (use_qrot)
        rope_q<<<dim3(B_ * H_), dim3(64), 0, stream>>>(query, pos, q_rot, invf_tab);

    const int wpb   = (cpp >= 2) ? 2 : 1;
    const int chunk = S_ / cpp;
    const size_t dynlds = (size_t)wpb * (8192 + 8 * chunk);
    pa_main<<<dim3(PAIRS * cpp / wpb), dim3(64 * wpb), dynlds, stream>>>(
        query, kc, vc, sm, pos, q_rot, invf_tab, ws_l, ws_acc, out, cpp, wpb, use_qrot);
    if (cpp > 1)
        pa_reduce<<<dim3(PAIRS), dim3(512), 0, stream>>>(ws_l, ws_acc, out, cpp);
}

// Round 2
// 549.671 us; speedup vs baseline: 1.0056x; 1.0056x over previous
//
#include <hip/hip_runtime.h>
#include <math.h>

#define B_    32
#define H_    32
#define KVH_  8
#define D_    128
#define S_    2048
#define REP   4            // H_/KVH_
#define PAIRS 256          // B_*KVH_
#define SCALE 0.08838834764831845f

typedef unsigned int u32;

// async global->LDS DMA, 16B per lane, lands at lds_base + lane*16
__device__ __forceinline__ void dma16(const float* g, float* l) {
    __builtin_amdgcn_global_load_lds(
        (const __attribute__((address_space(1))) u32*)g,
        (__attribute__((address_space(3))) u32*)l,
        16, 0, 0);
}

#define WAITVM(N) asm volatile("s_waitcnt vmcnt(" #N ")" ::: "memory")

// ---- one-shot q rope (double precision, matches reference path) + invf table ----
__global__ __launch_bounds__(64) void rope_q(
    const float* __restrict__ query,
    const int*   __restrict__ positions,
    float* __restrict__ q_rot,
    float* __restrict__ invf_tab)
{
    const int head = blockIdx.x;          // b*H_ + h
    const int b    = head >> 5;           // H_ = 32
    const int j    = threadIdx.x;         // freq index 0..63
    const double invf = exp(-(double)j * (9.210340371976184 / 64.0));
    if (head == 0) invf_tab[j] = (float)invf;
    const int posq = positions[b * S_ + (S_ - 1)];
    const double fr = (double)posq * invf;
    const float cs = (float)cos(fr), sn = (float)sin(fr);
    const float* q = query + (size_t)head * D_;
    const float lo = q[j], hi = q[64 + j];
    float* o = q_rot + (size_t)head * D_;
    o[j]      = (lo * cs - hi * sn) * SCALE;
    o[64 + j] = (hi * cs + lo * sn) * SCALE;
}

// k_cache/v_cache: [NUM_BLOCKS, 16, KVH, D] flat; token row stride = KVH*D = 1024 floats.
// One WAVE per chunk of S_/cpp tokens; 2 waves (2 chunks) per 128-thread block.
// Wave-private LDS: [3 bufs][k-lo 1KB | k-hi 1KB | v-lo 1KB | v-hi 1KB] + slot/pos arrays.
// Depth-3 DMA pipeline: prefetch distance 2, steady-state wait vmcnt(8).
extern __shared__ char smem_raw[];

__global__ __launch_bounds__(128, 4) void pa_main(
    const float* __restrict__ query,
    const float* __restrict__ k_cache,
    const float* __restrict__ v_cache,
    const int*   __restrict__ slot_map,
    const int*   __restrict__ positions,
    const float* __restrict__ q_rot,
    const float* __restrict__ invf_tab,
    float* __restrict__ ws_l,    // [PAIRS*cpp*4]
    float* __restrict__ ws_acc,  // [PAIRS*cpp*4*128]
    float* __restrict__ out,     // used when cpp==1
    int cpp, int wpb, int use_qrot)
{
    const int w     = threadIdx.x >> 6;
    const int ln    = threadIdx.x & 63;
    const int g     = ln & 15;            // dim group: dims [4g..4g+3] and [64+4g..64+4g+3]
    const int ts    = ln >> 4;            // token slot within pass (0..3)
    const int chunk = S_ / cpp;
    const int gch   = blockIdx.x * wpb + w;   // global chunk id
    const int pair  = gch / cpp;
    const int c     = gch - pair * cpp;
    const int b     = pair >> 3;
    const int kvh   = pair & 7;
    const int t0    = c * chunk;
    const int bS    = b * S_;
    const int passes = chunk >> 2;        // >= 2 for all supported cpp

    char*  wbase = smem_raw + (size_t)w * (12288 + 8 * chunk);
    float* buf   = (float*)wbase;             // 3 x 1024 floats (3 x 4KB)
    int*   ls    = (int*)(wbase + 12288);
    int*   lp    = ls + chunk;

    // ---- stage slot/pos for this wave's chunk into LDS (keeps loop VMEM = DMAs only) ----
    for (int t = ln; t < chunk; t += 64) {
        ls[t] = slot_map[bS + t0 + t];
        lp[t] = positions[bS + t0 + t];
    }

    // ---- q (already rope'd + scaled) and invf ----
    float ql[4][4], qh[4][4], invf[4];
    if (use_qrot) {
        float4 iv = ((const float4*)invf_tab)[g];
        invf[0] = iv.x; invf[1] = iv.y; invf[2] = iv.z; invf[3] = iv.w;
        #pragma unroll
        for (int hh = 0; hh < REP; hh++) {
            const float4* qb = (const float4*)(q_rot + (size_t)(b * H_ + kvh * REP + hh) * D_);
            float4 a = qb[g], cc = qb[16 + g];
            ql[hh][0] = a.x;  ql[hh][1] = a.y;  ql[hh][2] = a.z;  ql[hh][3] = a.w;
            qh[hh][0] = cc.x; qh[hh][1] = cc.y; qh[hh][2] = cc.z; qh[hh][3] = cc.w;
        }
    } else {
        // fallback: inline double-precision rope (workspace too small for q_rot)
        #pragma unroll
        for (int j = 0; j < 4; j++)
            invf[j] = (float)exp(-(double)(4 * g + j) * (9.210340371976184 / 64.0));
        const int posq = positions[bS + (S_ - 1)];
        #pragma unroll
        for (int hh = 0; hh < REP; hh++) {
            const float4* qb = (const float4*)(query + (size_t)(b * H_ + kvh * REP + hh) * D_);
            float4 a = qb[g], cc = qb[16 + g];
            float al[4] = {a.x, a.y, a.z, a.w};
            float ah[4] = {cc.x, cc.y, cc.z, cc.w};
            #pragma unroll
            for (int j = 0; j < 4; j++) {
                double fr = (double)posq * exp(-(double)(4 * g + j) * (9.210340371976184 / 64.0));
                float cs = (float)cos(fr), sn = (float)sin(fr);
                ql[hh][j] = (al[j] * cs - ah[j] * sn) * SCALE;
                qh[hh][j] = (ah[j] * cs + al[j] * sn) * SCALE;
            }
        }
    }

    float acc_lo[4][4] = {};
    float acc_hi[4][4] = {};
    float lsum[4] = {0.f, 0.f, 0.f, 0.f};

    // issue the 4 DMA loads (K lo/hi, V lo/hi) for pass pi into buffer bi
    auto issue = [&](int pi, int bi) {
        const int tix = pi * 4 + ts;
        const int sl  = ls[tix];
        const int sc  = sl < 0 ? 0 : sl;
        const int ro  = (sc >> 4) * 16384 + (sc & 15) * 1024 + kvh * 128 + 4 * g;
        const float* kr = k_cache + ro;
        const float* vr = v_cache + ro;
        float* bp = buf + bi * 1024;
        dma16(kr,      bp);          // k dims [0..63]   -> f4 slot ln
        dma16(kr + 64, bp + 256);    // k dims [64..127] -> f4 slot 64+ln
        dma16(vr,      bp + 512);
        dma16(vr + 64, bp + 768);
    };

    // compute pass i from buffer bi (data already drained into LDS)
    auto compute = [&](int i, int bi) {
        const float4* bf4 = (const float4*)(buf + bi * 1024);
        float4 k1 = bf4[ln];
        float4 k2 = bf4[64 + ln];

        const int tix = i * 4 + ts;
        const int sl  = ls[tix];
        const float m  = (sl >= 0) ? 1.f : 0.f;
        const float pf = (float)lp[tix];

        float kl[4], kh[4];
        {
            float kx[4] = {k1.x, k1.y, k1.z, k1.w};
            float ky[4] = {k2.x, k2.y, k2.z, k2.w};
            #pragma unroll
            for (int j = 0; j < 4; j++) {
                float fr = pf * invf[j];
                float sn, cs;
                __sincosf(fr, &sn, &cs);
                kl[j] = (kx[j] * cs - ky[j] * sn) * m;
                kh[j] = (ky[j] * cs + kx[j] * sn) * m;
            }
        }

        float p[4];
        #pragma unroll
        for (int hh = 0; hh < 4; hh++) {
            float t = ql[hh][0] * kl[0];
            t += ql[hh][1] * kl[1];
            t += ql[hh][2] * kl[2];
            t += ql[hh][3] * kl[3];
            t += qh[hh][0] * kh[0];
            t += qh[hh][1] * kh[1];
            t += qh[hh][2] * kh[2];
            t += qh[hh][3] * kh[3];
            p[hh] = t;
        }
        #pragma unroll
        for (int hh = 0; hh < 4; hh++) {
            #pragma unroll
            for (int mm = 1; mm < 16; mm <<= 1)
                p[hh] += __shfl_xor(p[hh], mm);
        }

        // V read deferred until after the score reduce (lower register peak)
        float4 v1 = bf4[128 + ln];
        float4 v2 = bf4[192 + ln];
        float vx[4] = {v1.x * m, v1.y * m, v1.z * m, v1.w * m};
        float vy[4] = {v2.x * m, v2.y * m, v2.z * m, v2.w * m};

        #pragma unroll
        for (int hh = 0; hh < 4; hh++) {
            const float wgt = __expf(p[hh]);   // invalid slots: p==0 -> w==1, matches reference
            lsum[hh] += wgt;
            #pragma unroll
            for (int j = 0; j < 4; j++) {
                acc_lo[hh][j] += wgt * vx[j];
                acc_hi[hh][j] += wgt * vy[j];
            }
        }
    };

    // ---- depth-3 pipeline: prologue fills 2 buffers ----
    issue(0, 0);
    issue(1, 1);
    int cur = 0, nxt = 2;
    int i = 0;
    for (; i + 2 < passes; ++i) {
        issue(i + 2, nxt);
        nxt = (nxt == 2) ? 0 : nxt + 1;
        WAITVM(8);                          // pass-i DMAs drained; i+1, i+2 in flight
        __builtin_amdgcn_sched_barrier(0);
        compute(i, cur);
        cur = (cur == 2) ? 0 : cur + 1;
    }
    // ---- tail: passes-2 and passes-1, no further issues ----
    WAITVM(4);
    __builtin_amdgcn_sched_barrier(0);
    compute(passes - 2, cur);
    cur = (cur == 2) ? 0 : cur + 1;
    WAITVM(0);
    __builtin_amdgcn_sched_barrier(0);
    compute(passes - 1, cur);

    // ---- merge the 4 token slots within the wave ----
    #pragma unroll
    for (int hh = 0; hh < 4; hh++) {
        lsum[hh] += __shfl_xor(lsum[hh], 16);
        lsum[hh] += __shfl_xor(lsum[hh], 32);
        #pragma unroll
        for (int j = 0; j < 4; j++) {
            acc_lo[hh][j] += __shfl_xor(acc_lo[hh][j], 16);
            acc_lo[hh][j] += __shfl_xor(acc_lo[hh][j], 32);
            acc_hi[hh][j] += __shfl_xor(acc_hi[hh][j], 16);
            acc_hi[hh][j] += __shfl_xor(acc_hi[hh][j], 32);
        }
    }

    if (cpp > 1) {
        if (ln < 16) {
            const size_t base = (size_t)(pair * cpp + c) * 4;
            #pragma unroll
            for (int hh = 0; hh < 4; hh++) {
                float4* dst = (float4*)(ws_acc + (base + hh) * 128);
                dst[g]      = make_float4(acc_lo[hh][0], acc_lo[hh][1], acc_lo[hh][2], acc_lo[hh][3]);
                dst[16 + g] = make_float4(acc_hi[hh][0], acc_hi[hh][1], acc_hi[hh][2], acc_hi[hh][3]);
            }
            if (ln == 0)
                *(float4*)(ws_l + base) = make_float4(lsum[0], lsum[1], lsum[2], lsum[3]);
        }
    } else {
        if (ln < 16) {
            #pragma unroll
            for (int hh = 0; hh < 4; hh++) {
                const float r = 1.f / lsum[hh];
                float4* dst = (float4*)(out + (size_t)(b * H_ + kvh * REP + hh) * D_);
                dst[g]      = make_float4(acc_lo[hh][0] * r, acc_lo[hh][1] * r, acc_lo[hh][2] * r, acc_lo[hh][3] * r);
                dst[16 + g] = make_float4(acc_hi[hh][0] * r, acc_hi[hh][1] * r, acc_hi[hh][2] * r, acc_hi[hh][3] * r);
            }
        }
    }
}

__global__ __launch_bounds__(512) void pa_reduce(
    const float* __restrict__ ws_l,
    const float* __restrict__ ws_acc,
    float* __restrict__ out,
    int cpp)
{
    const int pair = blockIdx.x;
    const int b = pair >> 3, kvh = pair & 7;
    const int hh = threadIdx.x >> 7;
    const int d  = threadIdx.x & 127;
    float a = 0.f;
    for (int s = 0; s < cpp; s++)
        a += ws_acc[((size_t)(pair * cpp + s) * 4 + hh) * 128 + d];
    float lt = 0.f;
    for (int s = 0; s < cpp; s++)
        lt += ws_l[(pair * cpp + s) * 4 + hh];
    out[((size_t)(b * H_ + kvh * REP + hh)) * D_ + d] = a / lt;
}

extern "C" void kernel_launch(void* const* d_in, const int* in_sizes, int n_in,
                              void* d_out, int out_size, void* d_ws, size_t ws_size,
                              hipStream_t stream) {
    const float* query = (const float*)d_in[0];
    const float* kc    = (const float*)d_in[1];
    const float* vc    = (const float*)d_in[2];
    const int*   sm    = (const int*)d_in[3];
    const int*   pos   = (const int*)d_in[4];
    float* out = (float*)d_out;

    const size_t qrot_f = (size_t)B_ * H_ * D_ + 64;   // q_rot + invf table (floats)
    int cpp = 1;
    int use_qrot = 0;
    const int cands[5] = {32, 16, 8, 4, 2};
    for (int ci = 0; ci < 5; ci++) {
        size_t need = (qrot_f + (size_t)PAIRS * cands[ci] * 516) * sizeof(float);
        if (ws_size >= need) { cpp = cands[ci]; use_qrot = 1; break; }
    }
    if (cpp == 1 && ws_size >= qrot_f * sizeof(float)) use_qrot = 1;

    float* q_rot    = (float*)d_ws;
    float* invf_tab = q_rot + (size_t)B_ * H_ * D_;
    float* ws_l     = use_qrot ? (invf_tab + 64) : (float*)d_ws;
    float* ws_acc   = ws_l + (size_t)PAIRS * cpp * 4;

    if (use_qrot)
        rope_q<<<dim3(B_ * H_), dim3(64), 0, stream>>>(query, pos, q_rot, invf_tab);

    const int wpb   = (cpp >= 2) ? 2 : 1;
    const int chunk = S_ / cpp;
    const size_t dynlds = (size_t)wpb * (12288 + 8 * chunk);
    pa_main<<<dim3(PAIRS * cpp / wpb), dim3(64 * wpb), dynlds, stream>>>(
        query, kc, vc, sm, pos, q_rot, invf_tab, ws_l, ws_acc, out, cpp, wpb, use_qrot);
    if (cpp > 1)
        pa_reduce<<<dim3(PAIRS), dim3(512), 0, stream>>>(ws_l, ws_acc, out, cpp);
}

// Round 3
// 534.024 us; speedup vs baseline: 1.0351x; 1.0293x over previous
//
#include <hip/hip_runtime.h>
#include <math.h>

#define B_    32
#define H_    32
#define KVH_  8
#define D_    128
#define S_    2048
#define REP   4            // H_/KVH_
#define PAIRS 256          // B_*KVH_
#define SCALE 0.08838834764831845f

// ---- one-shot q rope (double precision, matches reference path) + invf table ----
__global__ __launch_bounds__(64) void rope_q(
    const float* __restrict__ query,
    const int*   __restrict__ positions,
    float* __restrict__ q_rot,
    float* __restrict__ invf_tab)
{
    const int head = blockIdx.x;          // b*H_ + h
    const int b    = head >> 5;           // H_ = 32
    const int j    = threadIdx.x;         // freq index 0..63
    const double invf = exp(-(double)j * (9.210340371976184 / 64.0));
    if (head == 0) invf_tab[j] = (float)invf;
    const int posq = positions[b * S_ + (S_ - 1)];
    const double fr = (double)posq * invf;
    const float cs = (float)cos(fr), sn = (float)sin(fr);
    const float* q = query + (size_t)head * D_;
    const float lo = q[j], hi = q[64 + j];
    float* o = q_rot + (size_t)head * D_;
    o[j]      = (lo * cs - hi * sn) * SCALE;
    o[64 + j] = (hi * cs + lo * sn) * SCALE;
}

// k_cache/v_cache: [NUM_BLOCKS, 16, KVH, D] flat; token row stride = KVH*D = 1024 floats.
// One WAVE per chunk of S_/cpp tokens; wpb waves per block.
// K/V staged in a depth-4 rotating REGISTER buffer (16 VGPR/pass); compiler inserts
// exact counted vmcnt waits from the register dependencies — ~3.75 passes in flight.
// LDS holds only the per-wave slot/pos arrays (8*chunk bytes).
extern __shared__ char smem_raw[];

__global__ __launch_bounds__(128) void pa_main(
    const float* __restrict__ query,
    const float* __restrict__ k_cache,
    const float* __restrict__ v_cache,
    const int*   __restrict__ slot_map,
    const int*   __restrict__ positions,
    const float* __restrict__ q_rot,
    const float* __restrict__ invf_tab,
    float* __restrict__ ws_l,    // [PAIRS*cpp*4]
    float* __restrict__ ws_acc,  // [PAIRS*cpp*4*128]
    float* __restrict__ out,     // used when cpp==1
    int cpp, int wpb, int use_qrot)
{
    const int w     = threadIdx.x >> 6;
    const int ln    = threadIdx.x & 63;
    const int g     = ln & 15;            // dim group: dims [4g..4g+3] and [64+4g..64+4g+3]
    const int ts    = ln >> 4;            // token slot within pass (0..3)
    const int chunk = S_ / cpp;
    const int gch   = blockIdx.x * wpb + w;   // global chunk id
    const int pair  = gch / cpp;
    const int c     = gch - pair * cpp;
    const int b     = pair >> 3;
    const int kvh   = pair & 7;
    const int t0    = c * chunk;
    const int bS    = b * S_;
    const int passes = chunk >> 2;        // multiple of 4 for all supported cpp

    int* ls = (int*)(smem_raw + (size_t)w * (8 * chunk));
    int* lp = ls + chunk;

    // ---- stage slot/pos for this wave's chunk into LDS (wave-private; no barrier needed) ----
    for (int t = ln; t < chunk; t += 64) {
        ls[t] = slot_map[bS + t0 + t];
        lp[t] = positions[bS + t0 + t];
    }

    // ---- q (already rope'd + scaled) and invf ----
    float ql[4][4], qh[4][4], invf[4];
    if (use_qrot) {
        float4 iv = ((const float4*)invf_tab)[g];
        invf[0] = iv.x; invf[1] = iv.y; invf[2] = iv.z; invf[3] = iv.w;
        #pragma unroll
        for (int hh = 0; hh < REP; hh++) {
            const float4* qb = (const float4*)(q_rot + (size_t)(b * H_ + kvh * REP + hh) * D_);
            float4 a = qb[g], cc = qb[16 + g];
            ql[hh][0] = a.x;  ql[hh][1] = a.y;  ql[hh][2] = a.z;  ql[hh][3] = a.w;
            qh[hh][0] = cc.x; qh[hh][1] = cc.y; qh[hh][2] = cc.z; qh[hh][3] = cc.w;
        }
    } else {
        // fallback: inline double-precision rope (workspace too small for q_rot)
        #pragma unroll
        for (int j = 0; j < 4; j++)
            invf[j] = (float)exp(-(double)(4 * g + j) * (9.210340371976184 / 64.0));
        const int posq = positions[bS + (S_ - 1)];
        #pragma unroll
        for (int hh = 0; hh < REP; hh++) {
            const float4* qb = (const float4*)(query + (size_t)(b * H_ + kvh * REP + hh) * D_);
            float4 a = qb[g], cc = qb[16 + g];
            float al[4] = {a.x, a.y, a.z, a.w};
            float ah[4] = {cc.x, cc.y, cc.z, cc.w};
            #pragma unroll
            for (int j = 0; j < 4; j++) {
                double fr = (double)posq * exp(-(double)(4 * g + j) * (9.210340371976184 / 64.0));
                float cs = (float)cos(fr), sn = (float)sin(fr);
                ql[hh][j] = (al[j] * cs - ah[j] * sn) * SCALE;
                qh[hh][j] = (ah[j] * cs + al[j] * sn) * SCALE;
            }
        }
    }

    float acc_lo[4][4] = {};
    float acc_hi[4][4] = {};
    float lsum[4] = {0.f, 0.f, 0.f, 0.f};

    // depth-4 register pipeline
    float4 kb[4][2], vb[4][2];

    // load pass pi into slot s (s must be compile-time constant after unroll+inline)
    auto ldpass = [&](int pi, int s) {
        const int tix = pi * 4 + ts;
        const int sl  = ls[tix];
        const int sc  = sl < 0 ? 0 : sl;
        const size_t ro = (size_t)(sc >> 4) * 16384 + (size_t)(sc & 15) * 1024 + kvh * 128 + 4 * g;
        const float4* kr = (const float4*)(k_cache + ro);
        const float4* vr = (const float4*)(v_cache + ro);
        kb[s][0] = kr[0];  kb[s][1] = kr[16];
        vb[s][0] = vr[0];  vb[s][1] = vr[16];
    };

    // compute pass i from register slot s
    auto compute = [&](int i, int s) {
        const int tix = i * 4 + ts;
        const int sl  = ls[tix];
        const float m  = (sl >= 0) ? 1.f : 0.f;
        const float pf = (float)lp[tix];

        float kl[4], kh[4];
        {
            float kx[4] = {kb[s][0].x, kb[s][0].y, kb[s][0].z, kb[s][0].w};
            float ky[4] = {kb[s][1].x, kb[s][1].y, kb[s][1].z, kb[s][1].w};
            #pragma unroll
            for (int j = 0; j < 4; j++) {
                float fr = pf * invf[j];
                float sn, cs;
                __sincosf(fr, &sn, &cs);
                kl[j] = (kx[j] * cs - ky[j] * sn) * m;
                kh[j] = (ky[j] * cs + kx[j] * sn) * m;
            }
        }

        float p[4];
        #pragma unroll
        for (int hh = 0; hh < 4; hh++) {
            float t = ql[hh][0] * kl[0];
            t += ql[hh][1] * kl[1];
            t += ql[hh][2] * kl[2];
            t += ql[hh][3] * kl[3];
            t += qh[hh][0] * kh[0];
            t += qh[hh][1] * kh[1];
            t += qh[hh][2] * kh[2];
            t += qh[hh][3] * kh[3];
            p[hh] = t;
        }
        #pragma unroll
        for (int hh = 0; hh < 4; hh++) {
            #pragma unroll
            for (int mm = 1; mm < 16; mm <<= 1)
                p[hh] += __shfl_xor(p[hh], mm);
        }

        float vx[4] = {vb[s][0].x * m, vb[s][0].y * m, vb[s][0].z * m, vb[s][0].w * m};
        float vy[4] = {vb[s][1].x * m, vb[s][1].y * m, vb[s][1].z * m, vb[s][1].w * m};

        #pragma unroll
        for (int hh = 0; hh < 4; hh++) {
            const float wgt = __expf(p[hh]);   // invalid slots: p==0 -> w==1, matches reference
            lsum[hh] += wgt;
            #pragma unroll
            for (int j = 0; j < 4; j++) {
                acc_lo[hh][j] += wgt * vx[j];
                acc_hi[hh][j] += wgt * vy[j];
            }
        }
    };

    // ---- prologue: fill all 4 slots ----
    #pragma unroll
    for (int j = 0; j < 4; ++j)
        ldpass(j, j);

    // ---- main loop, unrolled x4 so slot indices are static ----
    for (int base = 0; base < passes; base += 4) {
        #pragma unroll
        for (int j = 0; j < 4; ++j) {
            const int i = base + j;
            compute(i, j);
            if (i + 4 < passes)
                ldpass(i + 4, j);
        }
    }

    // ---- merge the 4 token slots within the wave ----
    #pragma unroll
    for (int hh = 0; hh < 4; hh++) {
        lsum[hh] += __shfl_xor(lsum[hh], 16);
        lsum[hh] += __shfl_xor(lsum[hh], 32);
        #pragma unroll
        for (int j = 0; j < 4; j++) {
            acc_lo[hh][j] += __shfl_xor(acc_lo[hh][j], 16);
            acc_lo[hh][j] += __shfl_xor(acc_lo[hh][j], 32);
            acc_hi[hh][j] += __shfl_xor(acc_hi[hh][j], 16);
            acc_hi[hh][j] += __shfl_xor(acc_hi[hh][j], 32);
        }
    }

    if (cpp > 1) {
        if (ln < 16) {
            const size_t base = (size_t)(pair * cpp + c) * 4;
            #pragma unroll
            for (int hh = 0; hh < 4; hh++) {
                float4* dst = (float4*)(ws_acc + (base + hh) * 128);
                dst[g]      = make_float4(acc_lo[hh][0], acc_lo[hh][1], acc_lo[hh][2], acc_lo[hh][3]);
                dst[16 + g] = make_float4(acc_hi[hh][0], acc_hi[hh][1], acc_hi[hh][2], acc_hi[hh][3]);
            }
            if (ln == 0)
                *(float4*)(ws_l + base) = make_float4(lsum[0], lsum[1], lsum[2], lsum[3]);
        }
    } else {
        if (ln < 16) {
            #pragma unroll
            for (int hh = 0; hh < 4; hh++) {
                const float r = 1.f / lsum[hh];
                float4* dst = (float4*)(out + (size_t)(b * H_ + kvh * REP + hh) * D_);
                dst[g]      = make_float4(acc_lo[hh][0] * r, acc_lo[hh][1] * r, acc_lo[hh][2] * r, acc_lo[hh][3] * r);
                dst[16 + g] = make_float4(acc_hi[hh][0] * r, acc_hi[hh][1] * r, acc_hi[hh][2] * r, acc_hi[hh][3] * r);
            }
        }
    }
}

__global__ __launch_bounds__(512) void pa_reduce(
    const float* __restrict__ ws_l,
    const float* __restrict__ ws_acc,
    float* __restrict__ out,
    int cpp)
{
    const int pair = blockIdx.x;
    const int b = pair >> 3, kvh = pair & 7;
    const int hh = threadIdx.x >> 7;
    const int d  = threadIdx.x & 127;
    float a = 0.f;
    for (int s = 0; s < cpp; s++)
        a += ws_acc[((size_t)(pair * cpp + s) * 4 + hh) * 128 + d];
    float lt = 0.f;
    for (int s = 0; s < cpp; s++)
        lt += ws_l[(pair * cpp + s) * 4 + hh];
    out[((size_t)(b * H_ + kvh * REP + hh)) * D_ + d] = a / lt;
}

extern "C" void kernel_launch(void* const* d_in, const int* in_sizes, int n_in,
                              void* d_out, int out_size, void* d_ws, size_t ws_size,
                              hipStream_t stream) {
    const float* query = (const float*)d_in[0];
    const float* kc    = (const float*)d_in[1];
    const float* vc    = (const float*)d_in[2];
    const int*   sm    = (const int*)d_in[3];
    const int*   pos   = (const int*)d_in[4];
    float* out = (float*)d_out;

    const size_t qrot_f = (size_t)B_ * H_ * D_ + 64;   // q_rot + invf table (floats)
    int cpp = 1;
    int use_qrot = 0;
    const int cands[5] = {32, 16, 8, 4, 2};
    for (int ci = 0; ci < 5; ci++) {
        size_t need = (qrot_f + (size_t)PAIRS * cands[ci] * 516) * sizeof(float);
        if (ws_size >= need) { cpp = cands[ci]; use_qrot = 1; break; }
    }
    if (cpp == 1 && ws_size >= qrot_f * sizeof(float)) use_qrot = 1;

    float* q_rot    = (float*)d_ws;
    float* invf_tab = q_rot + (size_t)B_ * H_ * D_;
    float* ws_l     = use_qrot ? (invf_tab + 64) : (float*)d_ws;
    float* ws_acc   = ws_l + (size_t)PAIRS * cpp * 4;

    if (use_qrot)
        rope_q<<<dim3(B_ * H_), dim3(64), 0, stream>>>(query, pos, q_rot, invf_tab);

    const int wpb   = (cpp >= 2) ? 2 : 1;
    const int chunk = S_ / cpp;
    const size_t dynlds = (size_t)wpb * (8 * chunk);
    pa_main<<<dim3(PAIRS * cpp / wpb), dim3(64 * wpb), dynlds, stream>>>(
        query, kc, vc, sm, pos, q_rot, invf_tab, ws_l, ws_acc, out, cpp, wpb, use_qrot);
    if (cpp > 1)
        pa_reduce<<<dim3(PAIRS), dim3(512), 0, stream>>>(ws_l, ws_acc, out, cpp);
}